// Round 10
// baseline (1973.311 us; speedup 1.0000x reference)
//
#include <hip/hip_runtime.h>
#include <hip/hip_bf16.h>
#include <stdint.h>

#define TOK  8192
#define DIN  4096
#define DOUT 4096
#define NPL  3

typedef unsigned short u16;
typedef __attribute__((ext_vector_type(8))) __bf16 bf16x8;
typedef __attribute__((ext_vector_type(4))) float f32x4;
typedef __attribute__((ext_vector_type(4))) unsigned short u16x4;
typedef __attribute__((ext_vector_type(8))) unsigned short u16x8;

// ADC_MUL = (0.6/127) * 8020 * 256
#define ADC_MUL   9699.7795275590551f
#define INV256    0.00390625f

#define GL(src, dst) __builtin_amdgcn_global_load_lds( \
    (const __attribute__((address_space(1))) void*)(src), \
    (__attribute__((address_space(3))) void*)(dst), 16, 0, 0)

__device__ __forceinline__ u16 rne_bf16(float f) {
    uint32_t b = __float_as_uint(f);
    return (u16)((b + 0x7fffu + ((b >> 16) & 1u)) >> 16);
}

// ---------------- Kernel 1: DAC  x (f32) -> k (bf16 integer levels) ----------------
__global__ void dac_kernel(const float* __restrict__ x, u16* __restrict__ a) {
    const int n4 = TOK * DIN / 4;
    int i = blockIdx.x * blockDim.x + threadIdx.x;
    const int stride = gridDim.x * blockDim.x;
    const float4* xv = (const float4*)x;
    u16x4* av = (u16x4*)a;
    for (; i < n4; i += stride) {
        float4 v = xv[i];
        u16x4 o;
        float t, k;
        t = v.x * 0.15f; t = fminf(1.0f, fmaxf(-1.0f, t)); k = rintf(t * 127.0f);
        o.x = (u16)(__float_as_uint(k) >> 16);
        t = v.y * 0.15f; t = fminf(1.0f, fmaxf(-1.0f, t)); k = rintf(t * 127.0f);
        o.y = (u16)(__float_as_uint(k) >> 16);
        t = v.z * 0.15f; t = fminf(1.0f, fmaxf(-1.0f, t)); k = rintf(t * 127.0f);
        o.z = (u16)(__float_as_uint(k) >> 16);
        t = v.w * 0.15f; t = fminf(1.0f, fmaxf(-1.0f, t)); k = rintf(t * 127.0f);
        o.w = (u16)(__float_as_uint(k) >> 16);
        av[i] = o;
    }
}

// -------- Kernel 2: w_eff -> hi/lo bf16, layout W[o][p][kc][hi 64 | lo 64] ----------
// Same W layout as R8; rewritten for 16B stores (16 lanes cover one 256B hi|lo group).
__global__ void wsplit_kernel(const float* __restrict__ wp, const float* __restrict__ wn,
                              u16* __restrict__ w) {
    __shared__ float tile[64][65];                // tile[o][k], transposed on write
    const int b   = blockIdx.x;
    const int p   = b >> 12;
    const int rem = b & 4095;
    const int ib  = rem >> 6, ob = rem & 63;      // ib = kc chunk, ob = o-block
    const int t   = threadIdx.x;
    const size_t plane = (size_t)p * DIN * DOUT;

    {   // load 64(k) x 64(o), float4 over o; transpose into tile[o][k]
        const int o4 = (t & 15) << 2;
        const int r0 = t >> 4;
#pragma unroll
        for (int pass = 0; pass < 4; ++pass) {
            const int r = (pass << 4) + r0;       // k-row
            const size_t off = plane + (size_t)(ib * 64 + r) * DOUT + ob * 64 + o4;
            const float4 a = *(const float4*)(wp + off);
            const float4 c = *(const float4*)(wn + off);
            tile[o4 + 0][r] = a.x - c.x;
            tile[o4 + 1][r] = a.y - c.y;
            tile[o4 + 2][r] = a.z - c.z;
            tile[o4 + 3][r] = a.w - c.w;
        }
    }
    __syncthreads();
    // store: chunk c -> o = c>>4, half = (c&15)>>3, k8 = (c&7)*8 ; one u16x8 per chunk
#pragma unroll
    for (int pass = 0; pass < 4; ++pass) {
        const int c    = (pass << 8) + t;
        const int o    = c >> 4;
        const int sub  = c & 15;
        const int half = sub >> 3;
        const int k8   = (sub & 7) << 3;
        u16x8 ov;
#pragma unroll
        for (int j = 0; j < 8; ++j) {
            float d = tile[o][k8 + j];
            uint32_t db = __float_as_uint(d);
            uint32_t hb = (db + 0x7fffu + ((db >> 16) & 1u)) & 0xffff0000u;  // RNE bf16
            float l = d - __uint_as_float(hb);                                // exact
            u16 hi16 = (u16)(hb >> 16);
            u16 lo16 = rne_bf16(l);
            ov[j] = half ? lo16 : hi16;
        }
        const size_t idx = (size_t)(ob * 64 + o) * 24576 + (size_t)p * 8192
                         + ib * 128 + half * 64 + k8;
        *(u16x8*)(w + idx) = ov;
    }
}

// ---------------- Kernel 3: prefetch-overlap GEMM + ADC fold + bias ------------------
// BM=256 BN=128 BK(A)=64 feeding hi+lo; 8 waves (4M x 2N), wave 64x64.
// Dbuf LDS 128 KiB; R8 vmcnt ledger; phases issue NEXT frag reads, MFMA current regs.
#define READ_A(dst, base, koff)                                                         \
    _Pragma("unroll")                                                                   \
    for (int mi = 0; mi < 4; ++mi)                                                      \
        dst[mi] = *(const bf16x8*)((base) + aRd + (mi << 11) + (koff));
#define READ_B(dst, base, boff, koff)                                                   \
    _Pragma("unroll")                                                                   \
    for (int ni = 0; ni < 4; ++ni)                                                      \
        dst[ni] = *(const bf16x8*)((base) + (boff) + bRd + (ni << 11) + (koff));
#define MFMA16(Aset, Bset)                                                              \
    __builtin_amdgcn_s_setprio(1);                                                      \
    _Pragma("unroll")                                                                   \
    for (int mi = 0; mi < 4; ++mi)                                                      \
        _Pragma("unroll")                                                               \
        for (int ni = 0; ni < 4; ++ni)                                                  \
            acc[mi][ni] = __builtin_amdgcn_mfma_f32_16x16x32_bf16(                      \
                Aset[mi], Bset[ni], acc[mi][ni], 0, 0, 0);                              \
    __builtin_amdgcn_s_setprio(0);
#define SBAR  __builtin_amdgcn_sched_barrier(0)
#define LGKM0 asm volatile("s_waitcnt lgkmcnt(0)" ::: "memory")

__global__ __launch_bounds__(512, 2) void gemm_kernel(
    const u16* __restrict__ A,      // [8192][4096] bf16
    const u16* __restrict__ W,      // [4096][24576] bf16, [o][p][kc][hi64|lo64]
    const float* __restrict__ bias, // [4096]
    float* __restrict__ out)        // [8192][4096] f32
{
    __shared__ __align__(16) char lds[131072];
    // A buf0 @0, buf1 @32768 ; B buf0 @65536, buf1 @98304 (hi 16K | lo 16K each)

    const int bid = blockIdx.x;                   // 1024 blocks, bijective XCD swizzle
    const int g   = ((bid & 7) << 7) | (bid >> 3);
    const int mblk = g & 31, nblk = g >> 5;
    const int row0 = mblk << 8, col0 = nblk << 7;

    const int tid = threadIdx.x, lane = tid & 63, wid = tid >> 6;
    const int wm = wid >> 1, wn = wid & 1;        // 4 M-groups x 2 N-groups of 64

    const int swzb = (((tid & 7) ^ ((tid >> 3) & 7)) << 4);
    const char* gA = (const char*)A;
    const char* gB = (const char*)W;
    const size_t aRow = (size_t)(row0 + (tid >> 3)) * 8192 + swzb;
    const size_t bRow = (size_t)(col0 + (tid >> 3)) * 49152 + swzb;
    const int dstL = wid << 10;

    const int koff0 = (((lane >> 4) + 0) ^ (lane & 7)) << 4;
    const int koff1 = (((lane >> 4) + 4) ^ (lane & 7)) << 4;
    const int aRd = ((wm << 6) + (lane & 15)) << 7;
    const int bRd = ((wn << 6) + (lane & 15)) << 7;

    f32x4 acc[4][4], fin[4][4];
#pragma unroll
    for (int i = 0; i < 4; ++i)
#pragma unroll
        for (int j = 0; j < 4; ++j) {
            acc[i][j] = (f32x4){0.f, 0.f, 0.f, 0.f};
            fin[i][j] = (f32x4){0.f, 0.f, 0.f, 0.f};
        }

    auto stageA = [&](int it1, int j, char* dst) {
        GL(gA + aRow + ((size_t)j << 19) + ((size_t)(it1 & 63) << 7),
           dst + (j << 13) + dstL);
    };
    auto stageBhi = [&](int it1, int j, char* dst) {
        GL(gB + bRow + (size_t)it1 * 256 + ((size_t)j << 6) * 49152,
           dst + (j << 13) + dstL);
    };
    auto stageBlo = [&](int it1, int j, char* dst) {
        GL(gB + bRow + (size_t)it1 * 256 + 128 + ((size_t)j << 6) * 49152,
           dst + 16384 + (j << 13) + dstL);
    };

    bf16x8 fA0[4], fA1[4], fBa[4], fBb[4];

    // prologue: stage iter 0 -> buf0 (order A,A,A,A,Bhi,Bhi,Blo,Blo = R8 ledger);
    // vmcnt(2) leaves Blo(0) in flight; pre-read ph0 frags.
    {
        char* a0 = lds;
        char* b0 = lds + 65536;
        stageA(0, 0, a0); stageA(0, 1, a0); stageA(0, 2, a0); stageA(0, 3, a0);
        stageBhi(0, 0, b0); stageBhi(0, 1, b0);
        stageBlo(0, 0, b0); stageBlo(0, 1, b0);
        asm volatile("s_waitcnt vmcnt(2)" ::: "memory");
        __builtin_amdgcn_s_barrier();
        READ_A(fA0, lds, koff0);
        READ_B(fBa, lds + 65536, 0, koff0);
        LGKM0;
    }

    for (int it = 0; it < 192; ++it) {
        const int buf = it & 1;
        const char* lA  = lds + (buf << 15);
        const char* lB  = lds + 65536 + (buf << 15);
        char* sAn = lds + ((buf ^ 1) << 15);
        char* sBn = lds + 65536 + ((buf ^ 1) << 15);
        const bool st = (it < 191);

        // PH0: compute hi ks0 (A0 x Ba); prefetch fA1, fBb (buf hi ks1)
        if (st) { stageA(it + 1, 0, sAn); stageA(it + 1, 1, sAn); }
        READ_A(fA1, lA, koff1);
        READ_B(fBb, lB, 0, koff1);
        SBAR;
        MFMA16(fA0, fBa);
        SBAR; LGKM0;

        // PH1: compute hi ks1 (A1 x Bb); drain Blo(it); prefetch fBa (buf lo ks0)
        if (st) { stageA(it + 1, 2, sAn); stageA(it + 1, 3, sAn); }
        if (st) { asm volatile("s_waitcnt vmcnt(4)" ::: "memory"); }
        else    { asm volatile("s_waitcnt vmcnt(0)" ::: "memory"); }
        __builtin_amdgcn_s_barrier();
        READ_B(fBa, lB, 16384, koff0);
        SBAR;
        MFMA16(fA1, fBb);
        SBAR; LGKM0;

        // PH2: compute lo ks0 (A0 x Ba); prefetch fBb (buf lo ks1)
        if (st) { stageBhi(it + 1, 0, sBn); stageBhi(it + 1, 1, sBn); }
        READ_B(fBb, lB, 16384, koff1);
        SBAR;
        MFMA16(fA0, fBa);
        SBAR; LGKM0;

        // PH3: compute lo ks1 (A1 x Bb); drain A'(4)+Bhi'(2); prefetch next ph0 frags
        if (st) { stageBlo(it + 1, 0, sBn); stageBlo(it + 1, 1, sBn); }
        if (st) { asm volatile("s_waitcnt vmcnt(2)" ::: "memory"); }
        else    { asm volatile("s_waitcnt vmcnt(0)" ::: "memory"); }
        __builtin_amdgcn_s_barrier();
        READ_A(fA0, sAn, koff0);           // next buffer (just drained)
        READ_B(fBa, sBn, 0, koff0);
        SBAR;
        MFMA16(fA1, fBb);
        SBAR; LGKM0;

        if ((it & 63) == 63) {                        // plane boundary: ADC fold
            const float sh = (it == 63) ? 4.f : (it == 127) ? 2.f : 1.f;
#pragma unroll
            for (int mi = 0; mi < 4; ++mi)
#pragma unroll
                for (int ni = 0; ni < 4; ++ni)
#pragma unroll
                    for (int r = 0; r < 4; ++r) {
                        float q = rintf(acc[mi][ni][r] * ADC_MUL) * INV256;
                        q = fminf(16.0f, fmaxf(-16.0f, q));
                        fin[mi][ni][r] += sh * q;
                        acc[mi][ni][r] = 0.f;
                    }
        }
    }

    // epilogue: out = fin * 0.01 + bias  (C/D: col=lane&15, row=(lane>>4)*4+r)
    const int orow0 = row0 + (wm << 6) + ((lane >> 4) << 2);
    const int ocol0 = col0 + (wn << 6) + (lane & 15);
#pragma unroll
    for (int ni = 0; ni < 4; ++ni) {
        const int c = ocol0 + (ni << 4);
        const float bv = bias[c];
#pragma unroll
        for (int mi = 0; mi < 4; ++mi)
#pragma unroll
            for (int r = 0; r < 4; ++r)
                out[(size_t)(orow0 + (mi << 4) + r) * DOUT + c] = fin[mi][ni][r] * 0.01f + bv;
    }
}

extern "C" void kernel_launch(void* const* d_in, const int* in_sizes, int n_in,
                              void* d_out, int out_size, void* d_ws, size_t ws_size,
                              hipStream_t stream) {
    const float* x    = (const float*)d_in[0];
    const float* wp   = (const float*)d_in[1];
    const float* wn   = (const float*)d_in[2];
    const float* bias = (const float*)d_in[3];
    float* out = (float*)d_out;

    u16* A = (u16*)d_ws;                          // 8192*4096 bf16 = 67 MB
    u16* W = A + (size_t)TOK * DIN;               // 4096*24576 bf16 = 201 MB

    dac_kernel<<<dim3(4096), dim3(256), 0, stream>>>(x, A);
    wsplit_kernel<<<dim3(NPL * 64 * 64), dim3(256), 0, stream>>>(wp, wn, W);
    gemm_kernel<<<dim3(1024), dim3(512), 0, stream>>>(A, W, bias, out);
}

// Round 11
// 1858.915 us; speedup vs baseline: 1.0615x; 1.0615x over previous
//
#include <hip/hip_runtime.h>
#include <hip/hip_bf16.h>
#include <stdint.h>

#define TOK  8192
#define DIN  4096
#define DOUT 4096
#define NPL  3

typedef unsigned short u16;
typedef __attribute__((ext_vector_type(8))) __bf16 bf16x8;
typedef __attribute__((ext_vector_type(4))) float f32x4;
typedef __attribute__((ext_vector_type(4))) unsigned short u16x4;
typedef __attribute__((ext_vector_type(8))) unsigned short u16x8;

// ADC_MUL = (0.6/127) * 8020 * 256
#define ADC_MUL   9699.7795275590551f
#define INV256    0.00390625f

#define GL(src, dst) __builtin_amdgcn_global_load_lds( \
    (const __attribute__((address_space(1))) void*)(src), \
    (__attribute__((address_space(3))) void*)(dst), 16, 0, 0)

__device__ __forceinline__ u16 rne_bf16(float f) {
    uint32_t b = __float_as_uint(f);
    return (u16)((b + 0x7fffu + ((b >> 16) & 1u)) >> 16);
}

// ---------------- Kernel 1: DAC  x (f32) -> k (bf16 integer levels) ----------------
__global__ void dac_kernel(const float* __restrict__ x, u16* __restrict__ a) {
    const int n4 = TOK * DIN / 4;
    int i = blockIdx.x * blockDim.x + threadIdx.x;
    const int stride = gridDim.x * blockDim.x;
    const float4* xv = (const float4*)x;
    u16x4* av = (u16x4*)a;
    for (; i < n4; i += stride) {
        float4 v = xv[i];
        u16x4 o;
        float t, k;
        t = v.x * 0.15f; t = fminf(1.0f, fmaxf(-1.0f, t)); k = rintf(t * 127.0f);
        o.x = (u16)(__float_as_uint(k) >> 16);
        t = v.y * 0.15f; t = fminf(1.0f, fmaxf(-1.0f, t)); k = rintf(t * 127.0f);
        o.y = (u16)(__float_as_uint(k) >> 16);
        t = v.z * 0.15f; t = fminf(1.0f, fmaxf(-1.0f, t)); k = rintf(t * 127.0f);
        o.z = (u16)(__float_as_uint(k) >> 16);
        t = v.w * 0.15f; t = fminf(1.0f, fmaxf(-1.0f, t)); k = rintf(t * 127.0f);
        o.w = (u16)(__float_as_uint(k) >> 16);
        av[i] = o;
    }
}

// -------- Kernel 2: w_eff -> hi/lo bf16, layout W[o][p][kc][hi 64 | lo 64] ----------
__global__ void wsplit_kernel(const float* __restrict__ wp, const float* __restrict__ wn,
                              u16* __restrict__ w) {
    __shared__ float tile[64][65];                // tile[o][k], transposed on write
    const int b   = blockIdx.x;
    const int p   = b >> 12;
    const int rem = b & 4095;
    const int ib  = rem >> 6, ob = rem & 63;      // ib = kc chunk, ob = o-block
    const int t   = threadIdx.x;
    const size_t plane = (size_t)p * DIN * DOUT;

    {   // load 64(k) x 64(o), float4 over o; transpose into tile[o][k]
        const int o4 = (t & 15) << 2;
        const int r0 = t >> 4;
#pragma unroll
        for (int pass = 0; pass < 4; ++pass) {
            const int r = (pass << 4) + r0;       // k-row
            const size_t off = plane + (size_t)(ib * 64 + r) * DOUT + ob * 64 + o4;
            const float4 a = *(const float4*)(wp + off);
            const float4 c = *(const float4*)(wn + off);
            tile[o4 + 0][r] = a.x - c.x;
            tile[o4 + 1][r] = a.y - c.y;
            tile[o4 + 2][r] = a.z - c.z;
            tile[o4 + 3][r] = a.w - c.w;
        }
    }
    __syncthreads();
    // store: chunk c -> o = c>>4, half = (c&15)>>3, k8 = (c&7)*8 ; one u16x8 per chunk
#pragma unroll
    for (int pass = 0; pass < 4; ++pass) {
        const int c    = (pass << 8) + t;
        const int o    = c >> 4;
        const int sub  = c & 15;
        const int half = sub >> 3;
        const int k8   = (sub & 7) << 3;
        u16x8 ov;
#pragma unroll
        for (int j = 0; j < 8; ++j) {
            float d = tile[o][k8 + j];
            uint32_t db = __float_as_uint(d);
            uint32_t hb = (db + 0x7fffu + ((db >> 16) & 1u)) & 0xffff0000u;  // RNE bf16
            float l = d - __uint_as_float(hb);                                // exact
            u16 hi16 = (u16)(hb >> 16);
            u16 lo16 = rne_bf16(l);
            ov[j] = half ? lo16 : hi16;
        }
        const size_t idx = (size_t)(ob * 64 + o) * 24576 + (size_t)p * 8192
                         + ib * 128 + half * 64 + k8;
        *(u16x8*)(w + idx) = ov;
    }
}

// ---------------- Kernel 3: R8 skeleton, compiler-scheduled lgkm ladder --------------
// BM=256 BN=128 BK(A)=64 feeding hi+lo tiles; 8 waves (4M x 2N), wave 64x64.
// Double-buffered LDS 128 KiB; counted vmcnt(4)/(2); NO explicit lgkmcnt/sched_barrier:
// compiler emits dependency-driven counted lgkm waits (m97 behavior; m141 lesson).
// MFMA loop ni-outer so first 4 MFMAs need only bR[0] -> reads drain under MFMA.
#define PHASE(AREG, BOFF, KOFF, STAGE_STMT, WAIT_STMT)                                  \
    {                                                                                   \
        bf16x8 bR[4];                                                                   \
        _Pragma("unroll")                                                               \
        for (int ni = 0; ni < 4; ++ni)                                                  \
            bR[ni] = *(const bf16x8*)(lB + (BOFF) + bRd + (ni << 11) + (KOFF));         \
        STAGE_STMT;                                                                     \
        __builtin_amdgcn_s_barrier();                                                   \
        __builtin_amdgcn_s_setprio(1);                                                  \
        _Pragma("unroll")                                                               \
        for (int ni = 0; ni < 4; ++ni)                                                  \
            _Pragma("unroll")                                                           \
            for (int mi = 0; mi < 4; ++mi)                                              \
                acc[mi][ni] = __builtin_amdgcn_mfma_f32_16x16x32_bf16(                  \
                    AREG[mi], bR[ni], acc[mi][ni], 0, 0, 0);                            \
        __builtin_amdgcn_s_setprio(0);                                                  \
        WAIT_STMT;                                                                      \
        __builtin_amdgcn_s_barrier();                                                   \
    }

__global__ __launch_bounds__(512, 2) void gemm_kernel(
    const u16* __restrict__ A,      // [8192][4096] bf16
    const u16* __restrict__ W,      // [4096][24576] bf16, [o][p][kc][hi64|lo64]
    const float* __restrict__ bias, // [4096]
    float* __restrict__ out)        // [8192][4096] f32
{
    __shared__ __align__(16) char lds[131072];
    // A buf0 @0, buf1 @32768 (256r x 128B) ; B buf0 @65536, buf1 @98304 (hi 16K | lo 16K)

    const int bid = blockIdx.x;                   // 1024 blocks, 1024%8==0 -> bijective
    const int g   = ((bid & 7) << 7) | (bid >> 3);
    const int mblk = g & 31, nblk = g >> 5;
    const int row0 = mblk << 8, col0 = nblk << 7;

    const int tid = threadIdx.x, lane = tid & 63, wid = tid >> 6;
    const int wm = wid >> 1, wn = wid & 1;        // 4 M-groups x 2 N-groups of 64

    const int swzb = (((tid & 7) ^ ((tid >> 3) & 7)) << 4);
    const char* gA = (const char*)A;
    const char* gB = (const char*)W;
    const size_t aRow = (size_t)(row0 + (tid >> 3)) * 8192 + swzb;   // A row = 8192 B
    const size_t bRow = (size_t)(col0 + (tid >> 3)) * 49152 + swzb;  // W row = 49152 B
    const int dstL = wid << 10;

    const int koff0 = (((lane >> 4) + 0) ^ (lane & 7)) << 4;
    const int koff1 = (((lane >> 4) + 4) ^ (lane & 7)) << 4;
    const int aRd = ((wm << 6) + (lane & 15)) << 7;
    const int bRd = ((wn << 6) + (lane & 15)) << 7;

    f32x4 acc[4][4], fin[4][4];
#pragma unroll
    for (int i = 0; i < 4; ++i)
#pragma unroll
        for (int j = 0; j < 4; ++j) {
            acc[i][j] = (f32x4){0.f, 0.f, 0.f, 0.f};
            fin[i][j] = (f32x4){0.f, 0.f, 0.f, 0.f};
        }

    auto stageA = [&](int it1, int j, char* dst) {   // j-th 64-row slab of A chunk
        GL(gA + aRow + ((size_t)j << 19) + ((size_t)(it1 & 63) << 7),
           dst + (j << 13) + dstL);
    };
    auto stageBhi = [&](int it1, int j, char* dst) { // j-th 64-row slab, hi half
        GL(gB + bRow + (size_t)it1 * 256 + ((size_t)j << 6) * 49152,
           dst + (j << 13) + dstL);
    };
    auto stageBlo = [&](int it1, int j, char* dst) { // lo half (+128 B in source row)
        GL(gB + bRow + (size_t)it1 * 256 + 128 + ((size_t)j << 6) * 49152,
           dst + 16384 + (j << 13) + dstL);
    };

    // prologue: stage iteration 0 into buf0; drain A+Bhi (6 oldest), keep Blo in flight
    {
        char* a0 = lds;
        char* b0 = lds + 65536;
        stageA(0, 0, a0); stageA(0, 1, a0); stageA(0, 2, a0); stageA(0, 3, a0);
        stageBhi(0, 0, b0); stageBhi(0, 1, b0);
        stageBlo(0, 0, b0); stageBlo(0, 1, b0);
        asm volatile("s_waitcnt vmcnt(2)" ::: "memory");
        __builtin_amdgcn_s_barrier();
    }

    for (int it = 0; it < 192; ++it) {
        const int buf = it & 1;
        const char* lA = lds + (buf << 15);
        const char* lB = lds + 65536 + (buf << 15);
        char* sA1 = lds + ((buf ^ 1) << 15);
        char* sB1 = lds + 65536 + ((buf ^ 1) << 15);
        const bool st = (it < 191);

        bf16x8 aR0[4], aR1[4];
#pragma unroll
        for (int mi = 0; mi < 4; ++mi)
            aR0[mi] = *(const bf16x8*)(lA + aRd + (mi << 11) + koff0);
#pragma unroll
        for (int mi = 0; mi < 4; ++mi)
            aR1[mi] = *(const bf16x8*)(lA + aRd + (mi << 11) + koff1);

        // ph0: hi ks0   (stage next A slabs 0,1)
        PHASE(aR0, 0, koff0,
              { if (st) { stageA(it + 1, 0, sA1); stageA(it + 1, 1, sA1); } }, {});
        // ph1: hi ks1   (stage next A slabs 2,3; drain THIS iter's Blo)
        PHASE(aR1, 0, koff1,
              { if (st) { stageA(it + 1, 2, sA1); stageA(it + 1, 3, sA1); } },
              { if (st) asm volatile("s_waitcnt vmcnt(4)" ::: "memory");
                else    asm volatile("s_waitcnt vmcnt(0)" ::: "memory"); });
        // ph2: lo ks0   (stage next Bhi)
        PHASE(aR0, 16384, koff0,
              { if (st) { stageBhi(it + 1, 0, sB1); stageBhi(it + 1, 1, sB1); } }, {});
        // ph3: lo ks1   (stage next Blo; drain next iter's A+Bhi, keep its Blo)
        PHASE(aR1, 16384, koff1,
              { if (st) { stageBlo(it + 1, 0, sB1); stageBlo(it + 1, 1, sB1); } },
              { if (st) asm volatile("s_waitcnt vmcnt(2)" ::: "memory");
                else    asm volatile("s_waitcnt vmcnt(0)" ::: "memory"); });

        if ((it & 63) == 63) {                        // plane boundary: ADC fold
            const float sh = (it == 63) ? 4.f : (it == 127) ? 2.f : 1.f;
#pragma unroll
            for (int mi = 0; mi < 4; ++mi)
#pragma unroll
                for (int ni = 0; ni < 4; ++ni)
#pragma unroll
                    for (int r = 0; r < 4; ++r) {
                        float q = rintf(acc[mi][ni][r] * ADC_MUL) * INV256;
                        q = fminf(16.0f, fmaxf(-16.0f, q));
                        fin[mi][ni][r] += sh * q;
                        acc[mi][ni][r] = 0.f;
                    }
        }
    }

    // epilogue: out = fin * 0.01 + bias  (C/D: col=lane&15, row=(lane>>4)*4+r)
    const int orow0 = row0 + (wm << 6) + ((lane >> 4) << 2);
    const int ocol0 = col0 + (wn << 6) + (lane & 15);
#pragma unroll
    for (int ni = 0; ni < 4; ++ni) {
        const int c = ocol0 + (ni << 4);
        const float bv = bias[c];
#pragma unroll
        for (int mi = 0; mi < 4; ++mi)
#pragma unroll
            for (int r = 0; r < 4; ++r)
                out[(size_t)(orow0 + (mi << 4) + r) * DOUT + c] = fin[mi][ni][r] * 0.01f + bv;
    }
}

extern "C" void kernel_launch(void* const* d_in, const int* in_sizes, int n_in,
                              void* d_out, int out_size, void* d_ws, size_t ws_size,
                              hipStream_t stream) {
    const float* x    = (const float*)d_in[0];
    const float* wp   = (const float*)d_in[1];
    const float* wn   = (const float*)d_in[2];
    const float* bias = (const float*)d_in[3];
    float* out = (float*)d_out;

    u16* A = (u16*)d_ws;                          // 8192*4096 bf16 = 67 MB
    u16* W = A + (size_t)TOK * DIN;               // 4096*24576 bf16 = 201 MB

    dac_kernel<<<dim3(4096), dim3(256), 0, stream>>>(x, A);
    wsplit_kernel<<<dim3(NPL * 64 * 64), dim3(256), 0, stream>>>(wp, wn, W);
    gemm_kernel<<<dim3(1024), dim3(512), 0, stream>>>(A, W, bias, out);
}